// Round 6
// baseline (39.408 us; speedup 1.0000x reference)
//
#include <hip/hip_runtime.h>
#include <hip/hip_bf16.h>

#define HGT 128
#define WID 128
#define HW  (HGT * WID)          // 16384
#define CCH 64
#define NHEADS 4
#define NA 36                    // HEADS * KK
#define NB 4

typedef __attribute__((ext_vector_type(8))) short bf16x8;
typedef __attribute__((ext_vector_type(4))) float f32x4;
typedef __attribute__((ext_vector_type(4))) unsigned short u16x4;

// workspace layout (float offsets)
// WF: 20 weight-frag tiles (8 for v-GEMM, 12 for attn-GEMM), each 64 lanes x 8 bf16
#define WF_OFF   0               // 20*64*8 ushort = 5120 floats
#define BA_OFF   5120            // 48 floats (reduced attn bias, padded)
#define V_OFF    5184            // v bf16 px-major: B*HW*64 ushort = 2097152 floats
#define ATTN_OFF (5184 + 2097152)// attn fp32 ch-major: B*36*HW floats

__device__ inline short f2bf(float f) {
    // round-to-nearest-even bf16
    unsigned u = __float_as_uint(f);
    unsigned r = (u + 0x7fffu + ((u >> 16) & 1u)) >> 16;
    return (short)r;
}
__device__ inline float bf2f(unsigned short u) {
    return __uint_as_float(((unsigned)u) << 16);
}

// ---------------------------------------------------------------------------
// Prep kernel: build MFMA A-operand fragments (transposed weights) in the
// exact per-lane layout, bf16, plus the i-reduced attn bias.
// ---------------------------------------------------------------------------
__global__ void prep_kernel(const float* __restrict__ Wv,
                            const float* __restrict__ Wfg,
                            const float* __restrict__ bfg,
                            const float* __restrict__ Wbg,
                            const float* __restrict__ bbg,
                            float* __restrict__ ws) {
    int idx = blockIdx.x * 256 + threadIdx.x;
    unsigned short* wf = (unsigned short*)ws;
    if (idx < 20 * 64 * 8) {
        int j    = idx & 7;
        int lane = (idx >> 3) & 63;
        int t    = idx >> 9;
        int lo = lane & 15, hi = lane >> 4;
        float val;
        if (t < 8) {
            int nt = t >> 1, kf = t & 1;
            int k = kf * 32 + hi * 8 + j;
            int n = nt * 16 + lo;
            val = Wv[k * 64 + n];
        } else {
            int t2 = t - 8;
            int nt = t2 >> 2, kf = t2 & 3;
            int k = kf * 32 + hi * 8 + j;      // 0..127
            int n = nt * 16 + lo;              // 0..47
            if (n >= 36) {
                val = 0.f;
            } else {
                int h = n / 9, jj = n % 9;
                const float* W = (k < 64) ? Wfg : Wbg;
                int c = (k < 64) ? k : k - 64;
                float s = 0.f;
                #pragma unroll
                for (int i = 0; i < 9; i++) s += W[c * 324 + h * 81 + i * 9 + jj];
                val = s;
            }
        }
        wf[idx] = (unsigned short)f2bf(val);
    } else if (idx < 20 * 64 * 8 + 48) {
        int n = idx - 20 * 64 * 8;
        float s = 0.f;
        if (n < 36) {
            int h = n / 9, jj = n % 9;
            #pragma unroll
            for (int i = 0; i < 9; i++)
                s += bfg[h * 81 + i * 9 + jj] + bbg[h * 81 + i * 9 + jj];
        }
        ws[BA_OFF + n] = s;
    }
}

// ---------------------------------------------------------------------------
// Main projection kernel via bf16 MFMA (computes C^T so stores coalesce).
// Block = 4 waves; each wave owns one 16-pixel M-tile.
// v output: bf16, pixel-major [px_global][64] -> packed ushort4 stores.
// attn output: fp32, ch-major (unchanged).
// ---------------------------------------------------------------------------
__global__ __launch_bounds__(256) void proj_mfma(
        const float* __restrict__ x, const float* __restrict__ fg,
        const float* __restrict__ bg, const float* __restrict__ bv,
        const float* __restrict__ ws,
        unsigned short* __restrict__ v_bf, float* __restrict__ attn_out) {
    int tid  = threadIdx.x;
    int wave = tid >> 6, lane = tid & 63;
    int lo = lane & 15, hi = lane >> 4;

    int p0 = blockIdx.x * 64 + wave * 16;     // global 16-pixel tile base
    int b  = p0 >> 14;
    int l0 = p0 & (HW - 1);
    const size_t bin = (size_t)b * CCH * HW;

    // ---- weight A-frags: coalesced 16B loads, held in VGPRs ----
    const unsigned short* wf = (const unsigned short*)ws;
    bf16x8 a1[8];
    #pragma unroll
    for (int t = 0; t < 8; t++)
        a1[t] = *(const bf16x8*)(wf + ((size_t)t * 64 + lane) * 8);
    bf16x8 a2[12];
    #pragma unroll
    for (int t = 0; t < 12; t++)
        a2[t] = *(const bf16x8*)(wf + ((size_t)(8 + t) * 64 + lane) * 8);

    int pix = l0 + lo;                        // in-image pixel
    size_t pg = (size_t)p0 + lo;              // global pixel incl. batch

    // ---- v GEMM ----
    const float* xp = x + bin + pix;
    bf16x8 bx[2];
    #pragma unroll
    for (int kf = 0; kf < 2; kf++)
        #pragma unroll
        for (int j = 0; j < 8; j++)
            bx[kf][j] = f2bf(xp[(size_t)(kf * 32 + hi * 8 + j) * HW]);

    f32x4 av[4];
    #pragma unroll
    for (int nt = 0; nt < 4; nt++)
        #pragma unroll
        for (int r = 0; r < 4; r++)
            av[nt][r] = bv[nt * 16 + hi * 4 + r];

    #pragma unroll
    for (int nt = 0; nt < 4; nt++) {
        av[nt] = __builtin_amdgcn_mfma_f32_16x16x32_bf16(a1[nt * 2 + 0], bx[0], av[nt], 0, 0, 0);
        av[nt] = __builtin_amdgcn_mfma_f32_16x16x32_bf16(a1[nt * 2 + 1], bx[1], av[nt], 0, 0, 0);
    }

    // packed bf16 stores: v_bf[pg*64 + ch], ch = nt*16 + hi*4 + r
    #pragma unroll
    for (int nt = 0; nt < 4; nt++) {
        u16x4 pk;
        #pragma unroll
        for (int r = 0; r < 4; r++) pk[r] = (unsigned short)f2bf(av[nt][r]);
        *(u16x4*)(v_bf + pg * 64 + nt * 16 + hi * 4) = pk;
    }

    // ---- attn GEMM (K = 128: fg channels then bg channels) ----
    const float* fp = fg + bin + pix;
    const float* gp = bg + bin + pix;
    bf16x8 b2[4];
    #pragma unroll
    for (int kf = 0; kf < 2; kf++)
        #pragma unroll
        for (int j = 0; j < 8; j++)
            b2[kf][j] = f2bf(fp[(size_t)(kf * 32 + hi * 8 + j) * HW]);
    #pragma unroll
    for (int kf = 0; kf < 2; kf++)
        #pragma unroll
        for (int j = 0; j < 8; j++)
            b2[2 + kf][j] = f2bf(gp[(size_t)(kf * 32 + hi * 8 + j) * HW]);

    f32x4 aa[3];
    #pragma unroll
    for (int nt = 0; nt < 3; nt++)
        #pragma unroll
        for (int r = 0; r < 4; r++)
            aa[nt][r] = ws[BA_OFF + nt * 16 + hi * 4 + r];

    #pragma unroll
    for (int nt = 0; nt < 3; nt++)
        #pragma unroll
        for (int kf = 0; kf < 4; kf++)
            aa[nt] = __builtin_amdgcn_mfma_f32_16x16x32_bf16(a2[nt * 4 + kf], b2[kf], aa[nt], 0, 0, 0);

    float* ao = attn_out + (size_t)b * NA * HW + pix;
    #pragma unroll
    for (int nt = 0; nt < 3; nt++)
        #pragma unroll
        for (int r = 0; r < 4; r++) {
            int n = nt * 16 + hi * 4 + r;
            if (n < 36) ao[(size_t)n * HW] = aa[nt][r];
        }
}

// ---------------------------------------------------------------------------
// Aggregation: out[b][c][l] = sum_j attn[b][h(c)*9+j][l] * v[b][l+dj][c]
// One thread per (pixel, head); v read as 2x bf16x8 per neighbor.
// ---------------------------------------------------------------------------
__global__ __launch_bounds__(256) void agg_kernel(
        const unsigned short* __restrict__ v_bf, const float* __restrict__ attn,
        float* __restrict__ out) {
    int idx = blockIdx.x * 256 + threadIdx.x;     // B*4*HW threads
    int l = idx & (HW - 1);
    int rest = idx >> 14;
    int b = rest >> 2;
    int h = rest & 3;
    int y = l >> 7, xx = l & 127;

    const float* ab = attn + ((size_t)b * 36 + h * 9) * HW + l;
    float w[9];
    int off[9];
    #pragma unroll
    for (int j = 0; j < 9; j++) {
        w[j] = ab[(size_t)j * HW];
        int dy = j / 3 - 1, dx = j % 3 - 1;
        int yy = y + dy, xc = xx + dx;
        bool valid = (yy >= 0) && (yy < HGT) && (xc >= 0) && (xc < WID);
        off[j] = valid ? (yy * WID + xc) : l;
        if (!valid) w[j] = 0.f;
    }

    const unsigned short* vbase = v_bf + ((size_t)b * HW) * 64 + h * 16;
    float acc[16];
    #pragma unroll
    for (int c2 = 0; c2 < 16; c2++) acc[c2] = 0.f;

    #pragma unroll
    for (int j = 0; j < 9; j++) {
        const unsigned short* vp = vbase + (size_t)off[j] * 64;
        bf16x8 v0 = *(const bf16x8*)(vp);
        bf16x8 v1 = *(const bf16x8*)(vp + 8);
        float wj = w[j];
        #pragma unroll
        for (int k = 0; k < 8; k++) {
            acc[k]     += wj * bf2f((unsigned short)v0[k]);
            acc[8 + k] += wj * bf2f((unsigned short)v1[k]);
        }
    }

    float* ob = out + ((size_t)b * 64 + h * 16) * HW + l;
    #pragma unroll
    for (int c2 = 0; c2 < 16; c2++)
        ob[(size_t)c2 * HW] = acc[c2];
}

extern "C" void kernel_launch(void* const* d_in, const int* in_sizes, int n_in,
                              void* d_out, int out_size, void* d_ws, size_t ws_size,
                              hipStream_t stream) {
    const float* x   = (const float*)d_in[0];
    const float* fg  = (const float*)d_in[1];
    const float* bg  = (const float*)d_in[2];
    const float* Wv  = (const float*)d_in[3];
    const float* bv  = (const float*)d_in[4];
    const float* Wfg = (const float*)d_in[5];
    const float* bfg = (const float*)d_in[6];
    const float* Wbg = (const float*)d_in[7];
    const float* bbg = (const float*)d_in[8];

    float* ws  = (float*)d_ws;
    float* out = (float*)d_out;

    unsigned short* v_bf = (unsigned short*)(ws + V_OFF);
    float* attn_ws       = ws + ATTN_OFF;

    // 0) pack weight fragments + reduced bias
    prep_kernel<<<41, 256, 0, stream>>>(Wv, Wfg, bfg, Wbg, bbg, ws);

    // 1) MFMA projections: 64 pixels per block -> 1024 blocks
    proj_mfma<<<1024, 256, 0, stream>>>(x, fg, bg, bv, ws, v_bf, attn_ws);

    // 2) aggregation: one thread per (pixel, head)
    int np = NB * HW;                      // 65536
    agg_kernel<<<np * 4 / 256, 256, 0, stream>>>(v_bf, attn_ws, out);
}

// Round 7
// 31.234 us; speedup vs baseline: 1.2617x; 1.2617x over previous
//
#include <hip/hip_runtime.h>
#include <hip/hip_bf16.h>

#define HGT 128
#define WID 128
#define HW  (HGT * WID)          // 16384
#define CCH 64
#define NA 36                    // HEADS * KK
#define NB 4

// fused tiling
#define TILE_W 32
#define TILE_H 4
#define HALO_W 34                // TILE_W + 2
#define HALO_H 6                 // TILE_H + 2
#define NHP    204               // HALO_W * HALO_H
#define NGROUP 13                // ceil(NHP/16)
#define VSLOTS 208               // NGROUP*16

typedef __attribute__((ext_vector_type(8))) short bf16x8;
typedef __attribute__((ext_vector_type(4))) float f32x4;
typedef __attribute__((ext_vector_type(4))) unsigned short u16x4;

// workspace layout (float offsets)
#define WF_OFF   0               // 20*64*8 ushort = 5120 floats
#define BA_OFF   5120            // 48 floats (reduced attn bias, padded)

__device__ inline short f2bf(float f) {
    unsigned u = __float_as_uint(f);
    unsigned r = (u + 0x7fffu + ((u >> 16) & 1u)) >> 16;   // RNE
    return (short)r;
}
__device__ inline float bf2f(unsigned short u) {
    return __uint_as_float(((unsigned)u) << 16);
}

// ---------------------------------------------------------------------------
// Prep kernel: MFMA A-operand fragments (transposed weights) bf16, exact lane
// layout, plus i-reduced attn bias. (unchanged from R5 — proven correct)
// ---------------------------------------------------------------------------
__global__ void prep_kernel(const float* __restrict__ Wv,
                            const float* __restrict__ Wfg,
                            const float* __restrict__ bfg,
                            const float* __restrict__ Wbg,
                            const float* __restrict__ bbg,
                            float* __restrict__ ws) {
    int idx = blockIdx.x * 256 + threadIdx.x;
    unsigned short* wf = (unsigned short*)ws;
    if (idx < 20 * 64 * 8) {
        int j    = idx & 7;
        int lane = (idx >> 3) & 63;
        int t    = idx >> 9;
        int lo = lane & 15, hi = lane >> 4;
        float val;
        if (t < 8) {
            int nt = t >> 1, kf = t & 1;
            int k = kf * 32 + hi * 8 + j;
            int n = nt * 16 + lo;
            val = Wv[k * 64 + n];
        } else {
            int t2 = t - 8;
            int nt = t2 >> 2, kf = t2 & 3;
            int k = kf * 32 + hi * 8 + j;      // 0..127
            int n = nt * 16 + lo;              // 0..47
            if (n >= 36) {
                val = 0.f;
            } else {
                int h = n / 9, jj = n % 9;
                const float* W = (k < 64) ? Wfg : Wbg;
                int c = (k < 64) ? k : k - 64;
                float s = 0.f;
                #pragma unroll
                for (int i = 0; i < 9; i++) s += W[c * 324 + h * 81 + i * 9 + jj];
                val = s;
            }
        }
        wf[idx] = (unsigned short)f2bf(val);
    } else if (idx < 20 * 64 * 8 + 48) {
        int n = idx - 20 * 64 * 8;
        float s = 0.f;
        if (n < 36) {
            int h = n / 9, jj = n % 9;
            #pragma unroll
            for (int i = 0; i < 9; i++)
                s += bfg[h * 81 + i * 9 + jj] + bbg[h * 81 + i * 9 + jj];
        }
        ws[BA_OFF + n] = s;
    }
}

// ---------------------------------------------------------------------------
// Fused kernel: per 32x4 tile — v(halo) via MFMA -> LDS(bf16, swizzled),
// attn via MFMA -> LDS(fp32, stride 37), barrier, aggregate -> out.
// Block = 256 threads (4 waves). Grid = 512 (2 blocks/CU).
// ---------------------------------------------------------------------------
__global__ __launch_bounds__(256, 2) void fused_kernel(
        const float* __restrict__ x, const float* __restrict__ fg,
        const float* __restrict__ bg, const float* __restrict__ bv,
        const float* __restrict__ ws, float* __restrict__ out) {
    __shared__ unsigned short v_lds[VSLOTS * 64];     // 26.6 KB, swizzled rows
    __shared__ float attn_lds[TILE_W * TILE_H * 37];  // 18.9 KB

    int tid  = threadIdx.x;
    int wave = tid >> 6, lane = tid & 63;
    int lo = lane & 15, hi = lane >> 4;

    int bid = blockIdx.x;
    int b  = bid >> 7;                 // batch
    int t  = bid & 127;                // tile in image
    int ty = t >> 2, tx = t & 3;
    int y0 = ty * TILE_H, x0 = tx * TILE_W;
    const size_t bin = (size_t)b * CCH * HW;

    // ---- weight A-frags (VGPR-resident) ----
    const unsigned short* wf = (const unsigned short*)ws;
    bf16x8 a1[8];
    #pragma unroll
    for (int tt = 0; tt < 8; tt++)
        a1[tt] = *(const bf16x8*)(wf + ((size_t)tt * 64 + lane) * 8);
    bf16x8 a2[12];
    #pragma unroll
    for (int tt = 0; tt < 12; tt++)
        a2[tt] = *(const bf16x8*)(wf + ((size_t)(12 + tt - 4 + 0 + 0) * 64 + lane) * 8); // 8+tt
    // (clarity: a2[tt] tile index is 8+tt)
    #pragma unroll
    for (int tt = 0; tt < 12; tt++)
        a2[tt] = *(const bf16x8*)(wf + ((size_t)(8 + tt) * 64 + lane) * 8);

    // ================= Phase 1: v for halo pixels =================
    #pragma unroll
    for (int gi = 0; gi < 4; gi++) {
        int g = gi * 4 + wave;                    // wave-uniform
        if (g < NGROUP) {
            int hp  = g * 16 + lo;                // dest slot 0..207
            int hps = min(hp, NHP - 1);           // clamped source
            int rr = hps / HALO_W;
            int cc = hps - rr * HALO_W;
            int yy = min(max(y0 - 1 + rr, 0), HGT - 1);
            int xx = min(max(x0 - 1 + cc, 0), WID - 1);
            int l = yy * WID + xx;

            const float* xp = x + bin + l;
            bf16x8 bx[2];
            #pragma unroll
            for (int kf = 0; kf < 2; kf++)
                #pragma unroll
                for (int j = 0; j < 8; j++)
                    bx[kf][j] = f2bf(xp[(size_t)(kf * 32 + hi * 8 + j) * HW]);

            f32x4 av[4];
            #pragma unroll
            for (int nt = 0; nt < 4; nt++)
                #pragma unroll
                for (int r = 0; r < 4; r++)
                    av[nt][r] = bv[nt * 16 + hi * 4 + r];
            #pragma unroll
            for (int nt = 0; nt < 4; nt++) {
                av[nt] = __builtin_amdgcn_mfma_f32_16x16x32_bf16(a1[nt * 2 + 0], bx[0], av[nt], 0, 0, 0);
                av[nt] = __builtin_amdgcn_mfma_f32_16x16x32_bf16(a1[nt * 2 + 1], bx[1], av[nt], 0, 0, 0);
            }
            // swizzled LDS store: row hp, ch = nt*16 + hi*4 + r
            char* vb = (char*)v_lds;
            #pragma unroll
            for (int nt = 0; nt < 4; nt++) {
                u16x4 pk;
                #pragma unroll
                for (int r = 0; r < 4; r++) pk[r] = (unsigned short)f2bf(av[nt][r]);
                int byte = hp * 128 + ((nt * 32 + hi * 8) ^ ((hp & 7) << 4));
                *(u16x4*)(vb + byte) = pk;
            }
        }
    }

    // ================= Phase 2: attn for interior pixels =================
    #pragma unroll
    for (int gi = 0; gi < 2; gi++) {
        int gg = gi * 4 + wave;                   // 0..7
        int ip = gg * 16 + lo;                    // interior pixel 0..127
        int r = ip >> 5, c = ip & 31;
        int l = (y0 + r) * WID + x0 + c;

        const float* fp = fg + bin + l;
        const float* gp = bg + bin + l;
        bf16x8 b2[4];
        #pragma unroll
        for (int kf = 0; kf < 2; kf++)
            #pragma unroll
            for (int j = 0; j < 8; j++)
                b2[kf][j] = f2bf(fp[(size_t)(kf * 32 + hi * 8 + j) * HW]);
        #pragma unroll
        for (int kf = 0; kf < 2; kf++)
            #pragma unroll
            for (int j = 0; j < 8; j++)
                b2[2 + kf][j] = f2bf(gp[(size_t)(kf * 32 + hi * 8 + j) * HW]);

        f32x4 aa[3];
        #pragma unroll
        for (int nt = 0; nt < 3; nt++)
            #pragma unroll
            for (int r4 = 0; r4 < 4; r4++)
                aa[nt][r4] = ws[BA_OFF + nt * 16 + hi * 4 + r4];
        #pragma unroll
        for (int nt = 0; nt < 3; nt++)
            #pragma unroll
            for (int kf = 0; kf < 4; kf++)
                aa[nt] = __builtin_amdgcn_mfma_f32_16x16x32_bf16(a2[nt * 4 + kf], b2[kf], aa[nt], 0, 0, 0);

        // store to attn_lds[ip*37 + n], n = nt*16 + hi*4 + r
        float* ab = attn_lds + ip * 37;
        *(f32x4*)(ab + hi * 4)      = aa[0];
        *(f32x4*)(ab + 16 + hi * 4) = aa[1];
        if (hi == 0) *(f32x4*)(ab + 32) = aa[2];
    }

    __syncthreads();

    // ================= Phase 3: aggregation =================
    int ip    = tid & 127;
    int hpair = tid >> 7;                 // heads {2*hpair, 2*hpair+1}
    int r = ip >> 5, c = ip & 31;
    int y = y0 + r, xq = x0 + c;

    float acc[32];
    #pragma unroll
    for (int o = 0; o < 32; o++) acc[o] = 0.f;

    const char* vb = (const char*)v_lds;
    const float* ab = attn_lds + ip * 37 + hpair * 18;

    #pragma unroll
    for (int j = 0; j < 9; j++) {
        int dy = j / 3 - 1, dx = j % 3 - 1;
        bool valid = (unsigned)(y + dy) < HGT && (unsigned)(xq + dx) < WID;
        int tp = (r + 1 + dy) * HALO_W + (c + 1 + dx);   // halo slot
        float w0 = valid ? ab[j] : 0.f;
        float w1 = valid ? ab[9 + j] : 0.f;

        bf16x8 ch0, ch1, ch2, ch3;
        {
            int base = tp * 128;
            int sw = (tp & 7) << 4;
            int k0 = hpair * 4;
            ch0 = *(const bf16x8*)(vb + base + (((k0 + 0) * 16) ^ sw));
            ch1 = *(const bf16x8*)(vb + base + (((k0 + 1) * 16) ^ sw));
            ch2 = *(const bf16x8*)(vb + base + (((k0 + 2) * 16) ^ sw));
            ch3 = *(const bf16x8*)(vb + base + (((k0 + 3) * 16) ^ sw));
        }
        #pragma unroll
        for (int e = 0; e < 8; e++) {
            acc[e]      += w0 * bf2f((unsigned short)ch0[e]);
            acc[8 + e]  += w0 * bf2f((unsigned short)ch1[e]);
            acc[16 + e] += w1 * bf2f((unsigned short)ch2[e]);
            acc[24 + e] += w1 * bf2f((unsigned short)ch3[e]);
        }
    }

    float* ob = out + (size_t)b * CCH * HW + (size_t)(hpair * 32) * HW + y * WID + xq;
    #pragma unroll
    for (int o = 0; o < 32; o++)
        ob[(size_t)o * HW] = acc[o];
}

extern "C" void kernel_launch(void* const* d_in, const int* in_sizes, int n_in,
                              void* d_out, int out_size, void* d_ws, size_t ws_size,
                              hipStream_t stream) {
    const float* x   = (const float*)d_in[0];
    const float* fg  = (const float*)d_in[1];
    const float* bg  = (const float*)d_in[2];
    const float* Wv  = (const float*)d_in[3];
    const float* bv  = (const float*)d_in[4];
    const float* Wfg = (const float*)d_in[5];
    const float* bfg = (const float*)d_in[6];
    const float* Wbg = (const float*)d_in[7];
    const float* bbg = (const float*)d_in[8];

    float* ws  = (float*)d_ws;
    float* out = (float*)d_out;

    // 0) pack weight fragments + reduced bias
    prep_kernel<<<41, 256, 0, stream>>>(Wv, Wfg, bfg, Wbg, bbg, ws);

    // 1) fused v + attn + aggregation: 512 blocks (2/CU)
    fused_kernel<<<512, 256, 0, stream>>>(x, fg, bg, bv, ws, out);
}